// Round 3
// baseline (2475.655 us; speedup 1.0000x reference)
//
#include <hip/hip_runtime.h>
#include <math.h>

#define NN 8000   // nodes
#define CD 64     // node feature dim / C_OUT
#define DG 16     // neighbors per node
#define HD 128    // GRU hidden
#define G3 384    // 3*HD
#define TT 4      // walk steps
#define MARGIN 1e-3f   // f32-vs-f64 noisy-score safety margin (f32 path error ~1e-5)

__device__ __forceinline__ double sig64(double x){ return 1.0/(1.0+exp(-x)); }
__device__ __forceinline__ float  sig32(float  x){ return 1.f/(1.f+expf(-x)); }

// XG precompute: out[n][g] = b[g] + sum_c A[n][c]*W[c][g], accumulated in f64.
// Writes f64 table (if outd) and/or f32 table (if outf).
__global__ __launch_bounds__(384) void xg_kernel(const float* __restrict__ A,
    const float* __restrict__ W, const float* __restrict__ b,
    double* __restrict__ outd, float* __restrict__ outf)
{
    __shared__ float a_s[8][64];
    const int g  = threadIdx.x;        // 0..383
    const int n0 = blockIdx.x * 8;
    for (int idx = threadIdx.x; idx < 8*64; idx += 384)
        a_s[idx>>6][idx&63] = A[(size_t)n0*64 + idx];
    __syncthreads();
    double acc[8];
    const double bg = (double)b[g];
#pragma unroll
    for (int j=0;j<8;j++) acc[j] = bg;
    for (int c=0;c<64;c++){
        const double w = (double)W[c*G3 + g];
#pragma unroll
        for (int j=0;j<8;j++) acc[j] += (double)a_s[j][c]*w;
    }
#pragma unroll
    for (int j=0;j<8;j++){
        if (outd) outd[(size_t)(n0+j)*G3 + g] = acc[j];
        if (outf) outf[(size_t)(n0+j)*G3 + g] = (float)acc[j];
    }
}

__global__ void cvt_kernel(const float* __restrict__ s, double* __restrict__ d, int n){
    int i = blockIdx.x*blockDim.x + threadIdx.x;
    if (i < n) d[i] = (double)s[i];
}

// One wave (64 lanes) per node; 4 waves per block. Whole T-loop in one kernel.
// Recurrent chain (extend + h@Wh) stays f64; the 16-candidate scoring runs in
// f32 with an exact-f64 redo when the top-2 noisy margin is < MARGIN.
// NOTE: plain __launch_bounds__(256) — forcing min-waves=4 capped VGPR at 64
// and spilled ~44 MB to scratch (round 2: WRITE_SIZE 2.5->46.5 MB, 1.9 ms).
template<bool F32TAB>
__global__ __launch_bounds__(256) void walk_kernel(
    const int*   __restrict__ nbrs,  const float* __restrict__ noise,
    const double* __restrict__ XGd,  const float* __restrict__ XGf,
    const float* __restrict__ XGw,   const double* __restrict__ Wh64,
    const float* __restrict__ dbh,   const float* __restrict__ dWo, const float* __restrict__ dbo,
    const float* __restrict__ wWh,   const float* __restrict__ wbh,
    const float* __restrict__ wWo,   const float* __restrict__ wbo,
    float* __restrict__ out)
{
    __shared__ double h_s [4][HD];   // d-GRU hidden (f64), per wave
    __shared__ float  hf_s[4][HD];   // f32 mirror of h (fast candidate path)
    __shared__ float  hw_s[4][HD];   // w-GRU hidden (f32), per wave
    __shared__ double wo0_s [HD];    // dWo[:,0] f64
    __shared__ float  wo0f_s[HD];    // dWo[:,0] f32

    const int wid  = threadIdx.x >> 6;
    const int lane = threadIdx.x & 63;
    const int node = blockIdx.x*4 + wid;
    const int i0 = lane, i1 = lane + 64;

    if (threadIdx.x < HD){
        double w0 = (double)dWo[threadIdx.x*CD];
        wo0_s [threadIdx.x] = w0;
        wo0f_s[threadIdx.x] = (float)w0;
    }
    h_s [wid][i0] = 0.0;  h_s [wid][i1] = 0.0;
    hf_s[wid][i0] = 0.f;  hf_s[wid][i1] = 0.f;
    hw_s[wid][i0] = 0.f;  hw_s[wid][i1] = 0.f;

    // hg[m] = gate pre-act at index lane+64*m (r,z,n offsets are lane-congruent mod 64)
    double hg[6];  float hgw[6];
    double dbh_r[6]; float wbh_r[6];
#pragma unroll
    for (int m=0;m<6;m++){
        dbh_r[m] = (double)dbh[lane+64*m];
        wbh_r[m] = wbh[lane+64*m];
        hg[m]  = dbh_r[m];
        hgw[m] = wbh_r[m];
    }
    const double dbo0  = (double)dbo[0];
    const float  dbo0f = (float)dbo0;
    int cur = node;
    __syncthreads();

    for (int t=0;t<TT;t++){
        // ---- extend d-prefix (f64) and w-walk (f32) with attr[cur] ----
        const double* xg = XGd + (size_t)cur*G3;
        const float*  xw = XGw + (size_t)cur*G3;
        {
            double r = sig64(xg[i0]     + hg[0]);
            double z = sig64(xg[i0+128] + hg[2]);
            double n = tanh (xg[i0+256] + r*hg[4]);
            double hn0 = (1.0-z)*n + z*h_s[wid][i0];
            r = sig64(xg[i1]     + hg[1]);
            z = sig64(xg[i1+128] + hg[3]);
            n = tanh (xg[i1+256] + r*hg[5]);
            double hn1 = (1.0-z)*n + z*h_s[wid][i1];
            h_s [wid][i0]=hn0;        h_s [wid][i1]=hn1;
            hf_s[wid][i0]=(float)hn0; hf_s[wid][i1]=(float)hn1;
        }
        {
            float r = sig32(xw[i0]     + hgw[0]);
            float z = sig32(xw[i0+128] + hgw[2]);
            float n = tanhf(xw[i0+256] + r*hgw[4]);
            float hwn0 = (1.f-z)*n + z*hw_s[wid][i0];
            r = sig32(xw[i1]     + hgw[1]);
            z = sig32(xw[i1+128] + hgw[3]);
            n = tanhf(xw[i1+256] + r*hgw[5]);
            float hwn1 = (1.f-z)*n + z*hw_s[wid][i1];
            hw_s[wid][i0]=hwn0; hw_s[wid][i1]=hwn1;
        }
        __syncthreads();   // keep the block's 4 waves in lockstep on the weight stream

        // ---- matvecs: hg = dbh + h@dWh (f64) ; hgw = wbh + hw@wWh (f32) ----
        double acc[6]; float accw[6];
#pragma unroll
        for (int m=0;m<6;m++){ acc[m]=dbh_r[m]; accw[m]=wbh_r[m]; }
        {
            const double* wp  = Wh64 + lane;
            const float*  wwp = wWh  + lane;
#pragma unroll 4
            for (int k=0;k<HD;k++){
                const double hk  = h_s [wid][k];
                const float  hwk = hw_s[wid][k];
#pragma unroll
                for (int m=0;m<6;m++){
                    acc[m]  += hk  * wp [(size_t)k*G3 + 64*m];
                    accw[m] += hwk * wwp[(size_t)k*G3 + 64*m];
                }
            }
        }
        float hgf[6];
#pragma unroll
        for (int m=0;m<6;m++){ hg[m]=acc[m]; hgw[m]=accw[m]; hgf[m]=(float)acc[m]; }

        // ---- fast path: 16 candidates in f32 ----
        int   nbrv = (lane < DG) ? nbrs[(size_t)cur*DG + lane] : 0;
        float nz   = (lane < DG) ? noise[((size_t)t*NN + node)*DG + lane] : 0.f;
        float lf = -3.0e38f;                 // lane d (<16) keeps candidate d's logit
#pragma unroll 4
        for (int d=0; d<DG; d++){
            const int nd = __shfl(nbrv, d);
            float x0,x1,x2,x3,x4,x5;
            if (F32TAB){
                const float* xc = XGf + (size_t)nd*G3;
                x0=xc[i0]; x1=xc[i0+128]; x2=xc[i0+256];
                x3=xc[i1]; x4=xc[i1+128]; x5=xc[i1+256];
            } else {
                const double* xc = XGd + (size_t)nd*G3;
                x0=(float)xc[i0]; x1=(float)xc[i0+128]; x2=(float)xc[i0+256];
                x3=(float)xc[i1]; x4=(float)xc[i1+128]; x5=(float)xc[i1+256];
            }
            float r = sig32(x0 + hgf[0]);
            float z = sig32(x1 + hgf[2]);
            float n = tanhf(x2 + r*hgf[4]);
            float part = ((1.f-z)*n + z*hf_s[wid][i0]) * wo0f_s[i0];
            r = sig32(x3 + hgf[1]);
            z = sig32(x4 + hgf[3]);
            n = tanhf(x5 + r*hgf[5]);
            part += ((1.f-z)*n + z*hf_s[wid][i1]) * wo0f_s[i1];
#pragma unroll
            for (int off=32; off>0; off>>=1) part += __shfl_xor(part, off);
            if (lane == d) lf = part + dbo0f;
        }

        // ---- f32 softmax + noisy argmax + top-2 margin ----
        float v  = (lane < DG) ? lf : -3.0e38f;
        float mx = v;
#pragma unroll
        for (int off=32; off>0; off>>=1) mx = fmaxf(mx, __shfl_xor(mx, off));
        float e = (lane < DG) ? expf(v - mx) : 0.f;
        float s = e;
#pragma unroll
        for (int off=32; off>0; off>>=1) s += __shfl_xor(s, off);
        const float normf = mx + logf(s);

        float noisyf = (lane < DG) ? expf(v - normf) + 0.01f*nz : -3.0e38f;
        int   idx = lane;
        float bv  = noisyf;
#pragma unroll
        for (int off=32; off>0; off>>=1){
            float ov = __shfl_xor(bv, off);
            int   oi = __shfl_xor(idx, off);
            if (ov > bv || (ov == bv && oi < idx)){ bv = ov; idx = oi; }
        }
        float sv = (lane == idx || lane >= DG) ? -3.0e38f : noisyf;
#pragma unroll
        for (int off=32; off>0; off>>=1) sv = fmaxf(sv, __shfl_xor(sv, off));

        int    sel = idx;
        float  lpf = __shfl(v, sel) - normf;
        double lpd = 0.0;
        const bool need64 = (bv - sv) < MARGIN;   // wave-uniform

        // ---- exact f64 redo on near-ties (no barriers: wave-local only) ----
        if (need64){
            double lv = -1e300;
            for (int d=0; d<DG; d++){
                const int nd = __shfl(nbrv, d);
                const double* xc = XGd + (size_t)nd*G3;
                double r = sig64(xc[i0]     + hg[0]);
                double z = sig64(xc[i0+128] + hg[2]);
                double n = tanh (xc[i0+256] + r*hg[4]);
                double part = ((1.0-z)*n + z*h_s[wid][i0]) * wo0_s[i0];
                r = sig64(xc[i1]     + hg[1]);
                z = sig64(xc[i1+128] + hg[3]);
                n = tanh (xc[i1+256] + r*hg[5]);
                part += ((1.0-z)*n + z*h_s[wid][i1]) * wo0_s[i1];
#pragma unroll
                for (int off=32; off>0; off>>=1) part += __shfl_xor(part, off);
                if (lane == d) lv = part + dbo0;
            }
            double dv = (lane < DG) ? lv : -1e300;
            double dmx = dv;
#pragma unroll
            for (int off=32; off>0; off>>=1) dmx = fmax(dmx, __shfl_xor(dmx, off));
            double de = (lane < DG) ? exp(dv - dmx) : 0.0;
            double ds = de;
#pragma unroll
            for (int off=32; off>0; off>>=1) ds += __shfl_xor(ds, off);
            const double dnorm = dmx + log(ds);
            double dnoisy = (lane < DG) ? exp(dv - dnorm) + 0.01*(double)nz : -1e300;
            int di = lane;
#pragma unroll
            for (int off=32; off>0; off>>=1){
                double ov = __shfl_xor(dnoisy, off);
                int    oi = __shfl_xor(di, off);
                if (ov > dnoisy || (ov == dnoisy && oi < di)){ dnoisy = ov; di = oi; }
            }
            sel = di;
            lpd = __shfl(dv, sel) - dnorm;
        }

        if (lane == 0) out[NN*CD + node*TT + t] = need64 ? (float)lpd : lpf;
        cur = __shfl(nbrv, sel);
    }

    // ---- final w-extend with cur_T, then v_out = h_w @ wWo + wbo ----
    {
        const float* xw = XGw + (size_t)cur*G3;
        float r = sig32(xw[i0]     + hgw[0]);
        float z = sig32(xw[i0+128] + hgw[2]);
        float n = tanhf(xw[i0+256] + r*hgw[4]);
        float hwn0 = (1.f-z)*n + z*hw_s[wid][i0];
        r = sig32(xw[i1]     + hgw[1]);
        z = sig32(xw[i1+128] + hgw[3]);
        n = tanhf(xw[i1+256] + r*hgw[5]);
        float hwn1 = (1.f-z)*n + z*hw_s[wid][i1];
        hw_s[wid][i0]=hwn0; hw_s[wid][i1]=hwn1;
    }
    __syncthreads();
    {
        float acc = wbo[lane];                 // CD == 64 == wave width
        const float* wcol = wWo + lane;
        for (int i=0;i<HD;i++) acc += hw_s[wid][i] * wcol[(size_t)i*CD];
        out[(size_t)node*CD + lane] = acc;
    }
}

extern "C" void kernel_launch(void* const* d_in, const int* in_sizes, int n_in,
                              void* d_out, int out_size, void* d_ws, size_t ws_size,
                              hipStream_t stream)
{
    const float* attr  = (const float*)d_in[0];
    const int*   nbrs  = (const int*)  d_in[1];
    const float* noise = (const float*)d_in[2];
    const float* dWx = (const float*)d_in[3];
    const float* dWh = (const float*)d_in[4];
    const float* dbx = (const float*)d_in[5];
    const float* dbh = (const float*)d_in[6];
    const float* dWo = (const float*)d_in[7];
    const float* dbo = (const float*)d_in[8];
    const float* wWx = (const float*)d_in[9];
    const float* wWh = (const float*)d_in[10];
    const float* wbx = (const float*)d_in[11];
    const float* wbh = (const float*)d_in[12];
    const float* wWo = (const float*)d_in[13];
    const float* wbo = (const float*)d_in[14];
    float* out = (float*)d_out;

    char* ws = (char*)d_ws;
    const size_t need_f32tab = (size_t)NN*G3*16 + (size_t)HD*G3*8;   // ~49.5 MB
    const bool   f32tab = (ws_size >= need_f32tab);

    double* XGd = (double*)(ws);                          // 24.576 MB
    float*  XGw = (float*) (ws + (size_t)NN*G3*8);        // 12.288 MB
    float*  XGf;  double* Wh64;
    if (f32tab){
        XGf  = (float*) (ws + (size_t)NN*G3*12);          // 12.288 MB
        Wh64 = (double*)(ws + (size_t)NN*G3*16);          //  0.393 MB
    } else {
        XGf  = nullptr;
        Wh64 = (double*)(ws + (size_t)NN*G3*12);
    }

    xg_kernel<<<NN/8, G3, 0, stream>>>(attr, dWx, dbx, XGd, XGf);
    xg_kernel<<<NN/8, G3, 0, stream>>>(attr, wWx, wbx, nullptr, XGw);
    cvt_kernel<<<(HD*G3+255)/256, 256, 0, stream>>>(dWh, Wh64, HD*G3);

    if (f32tab)
        walk_kernel<true ><<<NN/4, 256, 0, stream>>>(nbrs, noise, XGd, XGf, XGw, Wh64,
                                                     dbh, dWo, dbo, wWh, wbh, wWo, wbo, out);
    else
        walk_kernel<false><<<NN/4, 256, 0, stream>>>(nbrs, noise, XGd, nullptr, XGw, Wh64,
                                                     dbh, dWo, dbo, wWh, wbh, wWo, wbo, out);
}

// Round 4
// 698.539 us; speedup vs baseline: 3.5440x; 3.5440x over previous
//
#include <hip/hip_runtime.h>
#include <math.h>

#define NN 8000   // nodes
#define CD 64     // node feature dim / C_OUT
#define DG 16     // neighbors per node
#define HD 128    // GRU hidden
#define G3 384    // 3*HD
#define TT 4      // walk steps
#define MARGIN 1e-4f   // f32 noisy-score error ~1e-6; 100x cushion

__device__ __forceinline__ double sig64(double x){ return 1.0/(1.0+exp(-x)); }
__device__ __forceinline__ float  sig32(float  x){ return 1.f/(1.f+expf(-x)); }

// XG precompute: out[n][g] = b[g] + sum_c A[n][c]*W[c][g], accumulated in f64.
__global__ __launch_bounds__(384) void xg_kernel(const float* __restrict__ A,
    const float* __restrict__ W, const float* __restrict__ b,
    double* __restrict__ outd, float* __restrict__ outf)
{
    __shared__ float a_s[8][64];
    const int g  = threadIdx.x;        // 0..383
    const int n0 = blockIdx.x * 8;
    for (int idx = threadIdx.x; idx < 8*64; idx += 384)
        a_s[idx>>6][idx&63] = A[(size_t)n0*64 + idx];
    __syncthreads();
    double acc[8];
    const double bg = (double)b[g];
#pragma unroll
    for (int j=0;j<8;j++) acc[j] = bg;
    for (int c=0;c<64;c++){
        const double w = (double)W[c*G3 + g];
#pragma unroll
        for (int j=0;j<8;j++) acc[j] += (double)a_s[j][c]*w;
    }
#pragma unroll
    for (int j=0;j<8;j++){
        if (outd) outd[(size_t)(n0+j)*G3 + g] = acc[j];
        if (outf) outf[(size_t)(n0+j)*G3 + g] = (float)acc[j];
    }
}

// One wave per node, 4 waves/block, NO barriers (waves fully independent).
// Everything f32; exact-f64 rebuild-from-scratch only when the top-2 noisy
// margin is < MARGIN (rare, ~1.5%/wave-step).
__global__ __launch_bounds__(256) void walk_kernel(
    const int*    __restrict__ nbrs, const float* __restrict__ noise,
    const double* __restrict__ XGd,  const float* __restrict__ XGf,
    const float*  __restrict__ dWh,  const float* __restrict__ dbh,
    const float*  __restrict__ dWo,  const float* __restrict__ dbo,
    int* __restrict__ paths, float* __restrict__ out)
{
    __shared__ float hf_s[4][HD];    // per-wave f32 hidden (own wave only)

    const int wid  = threadIdx.x >> 6;
    const int lane = threadIdx.x & 63;
    const int node = blockIdx.x*4 + wid;
    const int i0 = lane, i1 = lane + 64;

    float h0 = 0.f, h1 = 0.f;        // h[i0], h[i1]
    float dbhf[6], hgf[6];
#pragma unroll
    for (int m=0;m<6;m++){ dbhf[m] = dbh[lane+64*m]; hgf[m] = dbhf[m]; }
    const float wo0f0 = dWo[i0*CD];   // dWo[:,0] is lane-local
    const float wo0f1 = dWo[i1*CD];
    const float dbo0f = dbo[0];

    int cur = node;
    int ch0=0, ch1=0, ch2=0, ch3=0;   // cur at entry of each step (walk path)

    for (int t=0;t<TT;t++){
        if      (t==0) ch0 = cur;
        else if (t==1) ch1 = cur;
        else if (t==2) ch2 = cur;
        else           ch3 = cur;

        // ---- extend prefix with attr[cur] (f32) ----
        {
            const float* xg = XGf + (size_t)cur*G3;
            float r = sig32(xg[i0]     + hgf[0]);
            float z = sig32(xg[i0+128] + hgf[2]);
            float n = tanhf(xg[i0+256] + r*hgf[4]);
            h0 = (1.f-z)*n + z*h0;
            r = sig32(xg[i1]     + hgf[1]);
            z = sig32(xg[i1+128] + hgf[3]);
            n = tanhf(xg[i1+256] + r*hgf[5]);
            h1 = (1.f-z)*n + z*h1;
        }
        hf_s[wid][i0] = h0;  hf_s[wid][i1] = h1;

        // ---- matvec: hgf = dbh + h@dWh (f32, own-wave LDS broadcast) ----
        {
            float acc[6];
#pragma unroll
            for (int m=0;m<6;m++) acc[m] = dbhf[m];
            const float* wp = dWh + lane;
#pragma unroll 4
            for (int k=0;k<HD;k++){
                const float hk = hf_s[wid][k];
#pragma unroll
                for (int m=0;m<6;m++) acc[m] += hk * wp[(size_t)k*G3 + 64*m];
            }
#pragma unroll
            for (int m=0;m<6;m++) hgf[m] = acc[m];
        }

        // ---- 16 candidates (f32), 2 groups of 8 with prefetch ----
        int   nbrv = (lane < DG) ? nbrs[(size_t)cur*DG + lane] : 0;
        float nz   = (lane < DG) ? noise[((size_t)t*NN + node)*DG + lane] : 0.f;
        float lf = -3.0e38f;
#pragma unroll
        for (int g=0; g<2; g++){
            float xa[8],xb[8],xc2[8],xd[8],xe[8],xf[8];
#pragma unroll
            for (int j=0;j<8;j++){
                const int nd = __shfl(nbrv, g*8+j);
                const float* xc = XGf + (size_t)nd*G3;
                xa[j]=xc[i0]; xb[j]=xc[i0+128]; xc2[j]=xc[i0+256];
                xd[j]=xc[i1]; xe[j]=xc[i1+128]; xf[j]=xc[i1+256];
            }
            float part[8];
#pragma unroll
            for (int j=0;j<8;j++){
                float r = sig32(xa[j] + hgf[0]);
                float z = sig32(xb[j] + hgf[2]);
                float n = tanhf(xc2[j] + r*hgf[4]);
                part[j]  = ((1.f-z)*n + z*h0) * wo0f0;
                r = sig32(xd[j] + hgf[1]);
                z = sig32(xe[j] + hgf[3]);
                n = tanhf(xf[j] + r*hgf[5]);
                part[j] += ((1.f-z)*n + z*h1) * wo0f1;
            }
#pragma unroll
            for (int off=32; off>0; off>>=1){
#pragma unroll
                for (int j=0;j<8;j++) part[j] += __shfl_xor(part[j], off);
            }
#pragma unroll
            for (int j=0;j<8;j++) if (lane == g*8+j) lf = part[j] + dbo0f;
        }

        // ---- f32 softmax + noisy argmax + top-2 margin ----
        float v  = (lane < DG) ? lf : -3.0e38f;
        float mx = v;
#pragma unroll
        for (int off=32; off>0; off>>=1) mx = fmaxf(mx, __shfl_xor(mx, off));
        float e = (lane < DG) ? expf(v - mx) : 0.f;
        float s = e;
#pragma unroll
        for (int off=32; off>0; off>>=1) s += __shfl_xor(s, off);
        const float normf = mx + logf(s);

        float noisyf = (lane < DG) ? expf(v - normf) + 0.01f*nz : -3.0e38f;
        int   idx = lane;
        float bv  = noisyf;
#pragma unroll
        for (int off=32; off>0; off>>=1){
            float ov = __shfl_xor(bv, off);
            int   oi = __shfl_xor(idx, off);
            if (ov > bv || (ov == bv && oi < idx)){ bv = ov; idx = oi; }
        }
        float sv = (lane == idx || lane >= DG) ? -3.0e38f : noisyf;
#pragma unroll
        for (int off=32; off>0; off>>=1) sv = fmaxf(sv, __shfl_xor(sv, off));

        int   sel  = idx;
        float logp = __shfl(v, sel) - normf;

        // ---- rare: exact f64 rebuild-from-scratch (wave-local, no barriers) ----
        if ((bv - sv) < MARGIN){
            double H0 = 0.0, H1 = 0.0;
            double db64[6], g64[6];
#pragma unroll
            for (int m=0;m<6;m++){ db64[m] = (double)dbh[lane+64*m]; g64[m] = db64[m]; }
            const double wo0d0 = (double)dWo[i0*CD];
            const double wo0d1 = (double)dWo[i1*CD];
#pragma unroll
            for (int tt=0; tt<TT; tt++){
                if (tt <= t){
                    const int c = (tt==0)?ch0:(tt==1)?ch1:(tt==2)?ch2:ch3;
                    const double* xg = XGd + (size_t)c*G3;
                    double r = sig64(xg[i0]     + g64[0]);
                    double z = sig64(xg[i0+128] + g64[2]);
                    double n = tanh (xg[i0+256] + r*g64[4]);
                    H0 = (1.0-z)*n + z*H0;
                    r = sig64(xg[i1]     + g64[1]);
                    z = sig64(xg[i1+128] + g64[3]);
                    n = tanh (xg[i1+256] + r*g64[5]);
                    H1 = (1.0-z)*n + z*H1;
                    // f64 matvec, h broadcast via shfl (registers only)
#pragma unroll
                    for (int m=0;m<6;m++) g64[m] = db64[m];
                    for (int k=0;k<64;k++){
                        const double hk = __shfl(H0, k);
#pragma unroll
                        for (int m=0;m<6;m++)
                            g64[m] += hk * (double)dWh[(size_t)k*G3 + lane + 64*m];
                    }
                    for (int k=0;k<64;k++){
                        const double hk = __shfl(H1, k);
#pragma unroll
                        for (int m=0;m<6;m++)
                            g64[m] += hk * (double)dWh[(size_t)(k+64)*G3 + lane + 64*m];
                    }
                }
            }
            // f64 candidate scoring
            double lv = -1e300;
            for (int d=0; d<DG; d++){
                const int nd = __shfl(nbrv, d);
                const double* xc = XGd + (size_t)nd*G3;
                double r = sig64(xc[i0]     + g64[0]);
                double z = sig64(xc[i0+128] + g64[2]);
                double n = tanh (xc[i0+256] + r*g64[4]);
                double part = ((1.0-z)*n + z*H0) * wo0d0;
                r = sig64(xc[i1]     + g64[1]);
                z = sig64(xc[i1+128] + g64[3]);
                n = tanh (xc[i1+256] + r*g64[5]);
                part += ((1.0-z)*n + z*H1) * wo0d1;
#pragma unroll
                for (int off=32; off>0; off>>=1) part += __shfl_xor(part, off);
                if (lane == d) lv = part + (double)dbo0f;
            }
            double dv = (lane < DG) ? lv : -1e300;
            double dmx = dv;
#pragma unroll
            for (int off=32; off>0; off>>=1) dmx = fmax(dmx, __shfl_xor(dmx, off));
            double de = (lane < DG) ? exp(dv - dmx) : 0.0;
            double ds = de;
#pragma unroll
            for (int off=32; off>0; off>>=1) ds += __shfl_xor(ds, off);
            const double dnorm = dmx + log(ds);
            double dnoisy = (lane < DG) ? exp(dv - dnorm) + 0.01*(double)nz : -1e300;
            int di = lane;
#pragma unroll
            for (int off=32; off>0; off>>=1){
                double ov = __shfl_xor(dnoisy, off);
                int    oi = __shfl_xor(di, off);
                if (ov > dnoisy || (ov == dnoisy && oi < di)){ dnoisy = ov; di = oi; }
            }
            sel  = di;
            logp = (float)(__shfl(dv, sel) - dnorm);
        }

        if (lane == 0) out[NN*CD + node*TT + t] = logp;
        cur = __shfl(nbrv, sel);
    }

    if (lane == 0){
        int* p = paths + (size_t)node*8;
        p[0]=ch0; p[1]=ch1; p[2]=ch2; p[3]=ch3; p[4]=cur;
    }
}

// w-GRU over the recorded 5-node walk; pure throughput, no barriers.
__global__ __launch_bounds__(256) void wgru_kernel(
    const int*   __restrict__ paths, const float* __restrict__ XGw,
    const float* __restrict__ wWh,   const float* __restrict__ wbh,
    const float* __restrict__ wWo,   const float* __restrict__ wbo,
    float* __restrict__ out)
{
    __shared__ float hw_s[4][HD];
    const int wid  = threadIdx.x >> 6;
    const int lane = threadIdx.x & 63;
    const int node = blockIdx.x*4 + wid;
    const int i0 = lane, i1 = lane + 64;

    float h0 = 0.f, h1 = 0.f;
    float wb[6], hg[6];
#pragma unroll
    for (int m=0;m<6;m++){ wb[m] = wbh[lane+64*m]; hg[m] = wb[m]; }
    const int* p = paths + (size_t)node*8;

#pragma unroll
    for (int s=0; s<=TT; s++){
        const int c = p[s];
        const float* xw = XGw + (size_t)c*G3;
        float r = sig32(xw[i0]     + hg[0]);
        float z = sig32(xw[i0+128] + hg[2]);
        float n = tanhf(xw[i0+256] + r*hg[4]);
        h0 = (1.f-z)*n + z*h0;
        r = sig32(xw[i1]     + hg[1]);
        z = sig32(xw[i1+128] + hg[3]);
        n = tanhf(xw[i1+256] + r*hg[5]);
        h1 = (1.f-z)*n + z*h1;
        if (s < TT){
            hw_s[wid][i0] = h0;  hw_s[wid][i1] = h1;
            float acc[6];
#pragma unroll
            for (int m=0;m<6;m++) acc[m] = wb[m];
            const float* wp = wWh + lane;
#pragma unroll 4
            for (int k=0;k<HD;k++){
                const float hk = hw_s[wid][k];
#pragma unroll
                for (int m=0;m<6;m++) acc[m] += hk * wp[(size_t)k*G3 + 64*m];
            }
#pragma unroll
            for (int m=0;m<6;m++) hg[m] = acc[m];
        }
    }
    hw_s[wid][i0] = h0;  hw_s[wid][i1] = h1;

    float acc = wbo[lane];                 // CD == 64 == wave width
    const float* wcol = wWo + lane;
    for (int i=0;i<HD;i++) acc += hw_s[wid][i] * wcol[(size_t)i*CD];
    out[(size_t)node*CD + lane] = acc;
}

extern "C" void kernel_launch(void* const* d_in, const int* in_sizes, int n_in,
                              void* d_out, int out_size, void* d_ws, size_t ws_size,
                              hipStream_t stream)
{
    const float* attr  = (const float*)d_in[0];
    const int*   nbrs  = (const int*)  d_in[1];
    const float* noise = (const float*)d_in[2];
    const float* dWx = (const float*)d_in[3];
    const float* dWh = (const float*)d_in[4];
    const float* dbx = (const float*)d_in[5];
    const float* dbh = (const float*)d_in[6];
    const float* dWo = (const float*)d_in[7];
    const float* dbo = (const float*)d_in[8];
    const float* wWx = (const float*)d_in[9];
    const float* wWh = (const float*)d_in[10];
    const float* wbx = (const float*)d_in[11];
    const float* wbh = (const float*)d_in[12];
    const float* wWo = (const float*)d_in[13];
    const float* wbo = (const float*)d_in[14];
    float* out = (float*)d_out;

    char* ws = (char*)d_ws;
    double* XGd   = (double*)(ws);                          // 24.576 MB (redo only)
    float*  XGf   = (float*) (ws + (size_t)NN*G3*8);        // 12.288 MB
    float*  XGw   = (float*) (ws + (size_t)NN*G3*12);       // 12.288 MB
    int*    paths = (int*)   (ws + (size_t)NN*G3*16);       //  0.256 MB

    xg_kernel<<<NN/8, G3, 0, stream>>>(attr, dWx, dbx, XGd, XGf);
    xg_kernel<<<NN/8, G3, 0, stream>>>(attr, wWx, wbx, nullptr, XGw);

    walk_kernel<<<NN/4, 256, 0, stream>>>(nbrs, noise, XGd, XGf,
                                          dWh, dbh, dWo, dbo, paths, out);
    wgru_kernel<<<NN/4, 256, 0, stream>>>(paths, XGw, wWh, wbh, wWo, wbo, out);
}